// Round 1
// 321.905 us; speedup vs baseline: 1.1100x; 1.1100x over previous
//
#include <hip/hip_runtime.h>
#include <stdint.h>

#define TT 8192          // sequence length T
#define BT 16384         // B*T tokens
#define MCH 8192         // token chunk for qkv GEMM + attention

typedef __attribute__((ext_vector_type(8))) __bf16 bf16x8;
typedef __attribute__((ext_vector_type(4))) __bf16 bf16x4;
typedef __attribute__((ext_vector_type(4))) short short4v;
typedef __attribute__((ext_vector_type(4))) float floatx4;

__device__ __forceinline__ float bf2f(unsigned short h) {
  union { unsigned u; float f; } x; x.u = ((unsigned)h) << 16; return x.f;
}
__device__ __forceinline__ unsigned short f2bf(float f) {
  union { float f; unsigned u; } x; x.f = f;
  unsigned r = (x.u + 0x7fffu + ((x.u >> 16) & 1u)) >> 16;
  return (unsigned short)r;
}
__device__ __forceinline__ void async16(const void* g, void* l) {
  __builtin_amdgcn_global_load_lds(
      (__attribute__((address_space(1))) void*)g,
      (__attribute__((address_space(3))) void*)l, 16, 0, 0);
}

// ---------------------------------------------------------------------------
// fp32 -> bf16 conversion (round-to-nearest-even), float4 vectorized.
// ---------------------------------------------------------------------------
__global__ __launch_bounds__(256) void cvt_f2b(
    const float* __restrict__ src, unsigned short* __restrict__ dst, int n4) {
  const int i = blockIdx.x * 256 + threadIdx.x;
  if (i < n4) {
    const float4 f = ((const float4*)src)[i];
    union { uint2 u2; unsigned short s[4]; } o;
    o.s[0] = f2bf(f.x); o.s[1] = f2bf(f.y);
    o.s[2] = f2bf(f.z); o.s[3] = f2bf(f.w);
    ((uint2*)dst)[i] = o.u2;
  }
}

// ---------------------------------------------------------------------------
// RoPE cos/sin table: tab[t*32+p] = (cos, sin) of t * 10000^(-p/32)
// ---------------------------------------------------------------------------
__global__ __launch_bounds__(256) void rope_table_k(float2* __restrict__ tab) {
  const int i = blockIdx.x * 256 + threadIdx.x;
  if (i < TT * 32) {
    const int t = i >> 5, p = i & 31;
    const float f = (float)t * exp2f((float)p * -0.41524101186092f); // -log2(1e4)/32
    float s, c;
    sincosf(f, &s, &c);
    tab[i] = make_float2(c, s);
  }
}

// ---------------------------------------------------------------------------
// GEMM, 256x256 8-phase schedule (m201 template): C[M,N] = A[M,K] . W[N,K]^T
// BK=64, 8 waves (2M x 4N), 128 KiB double-buffered LDS, counted vmcnt(4)
// at K-tile boundaries only, XOR chunk-swizzle (chunk ^= row&7) applied to
// both the staging global source and the ds_read address (involution),
// setprio(1) around each 16-MFMA cluster, XCD-aware blockIdx swizzle.
// Requires: M%256==0, N%256==0, K%64==0, K/64>=2, grid%8==0.
// ---------------------------------------------------------------------------
template <bool CF32>
__global__ __launch_bounds__(512, 2) void gemm256(
    const unsigned short* __restrict__ A,
    const unsigned short* __restrict__ W,
    void* __restrict__ C,
    int M, int N, int K)
{
  // [buf][0]=A tile [256][64], [buf][1]=B tile [256][64]  (128 KiB total)
  __shared__ __align__(16) unsigned short sm[2][2][256 * 64];

  const int tid  = threadIdx.x;
  const int lane = tid & 63;
  const int wid  = tid >> 6;
  const int wr   = wid >> 2;          // 0..1 : wave row (M)
  const int wc   = wid & 3;           // 0..3 : wave col (N)
  const int lm   = lane & 15;
  const int kg   = lane >> 4;

  // XCD-aware swizzle (grid % 8 == 0 for both call sites -> bijective)
  const int nb  = N >> 8;
  const int cpx = (int)gridDim.x >> 3;
  const int bid = blockIdx.x;
  const int swz = (bid & 7) * cpx + (bid >> 3);
  const int bm  = swz / nb;
  const int bn  = swz % nb;

  const int NT = K >> 6;              // K-tiles of 64

  // staging geometry: per wave 2 x global_load_lds(16B); LDS dest is linear
  // (wave-uniform base + lane*16); global source column is pre-swizzled so
  // LDS(r, c) holds global chunk c ^ (r&7).
  const int srow = lane >> 3;                  // row within 8-row segment
  const int sc   = (lane & 7) ^ srow;          // swizzled source chunk

  auto stage = [&](const unsigned short* __restrict__ G, size_t grow0,
                   int kcol, unsigned short* lds) {
#pragma unroll
    for (int q = 0; q < 2; ++q) {
      const int seg = q * 8 + wid;             // 1 KiB segment index (0..15)
      const int r   = seg * 8 + srow;          // row 0..127 within half-tile
      async16(G + (grow0 + (size_t)r) * (size_t)K + kcol + sc * 8,
              (char*)lds + seg * 1024);
    }
  };

  floatx4 acc[8][4];
  floatx4 z = {0.f, 0.f, 0.f, 0.f};
#pragma unroll
  for (int i = 0; i < 8; ++i)
#pragma unroll
    for (int j = 0; j < 4; ++j) acc[i][j] = z;

  const size_t arow = (size_t)bm * 256;
  const size_t brow = (size_t)bn * 256;

  // ---- prologue: stage A(0), B(0), B(1); gate on tile-0 residency ----
  stage(A, arow,       0, &sm[0][0][0]);
  stage(A, arow + 128, 0, &sm[0][0][128 * 64]);
  stage(W, brow,       0, &sm[0][1][0]);
  stage(W, brow + 128, 0, &sm[0][1][128 * 64]);
  if (NT > 1) {
    stage(W, brow,       64, &sm[1][1][0]);
    stage(W, brow + 128, 64, &sm[1][1][128 * 64]);
  }
  asm volatile("s_waitcnt vmcnt(4)" ::: "memory");
  __builtin_amdgcn_s_barrier();
  __builtin_amdgcn_sched_barrier(0);

  const int cxor = lm & 7;            // row-dependent read swizzle term

  for (int t = 0; t < NT; ++t) {
    const int buf = t & 1;
    const unsigned short* Ab = &sm[buf][0][0];
    const unsigned short* Bb = &sm[buf][1][0];
    bf16x8 bfrag[4][2];

#pragma unroll
    for (int p = 0; p < 4; ++p) {
      // ---- ds-read register subtile for this phase ----
      bf16x8 afrag[2][2];
#pragma unroll
      for (int ii = 0; ii < 2; ++ii) {
        const int rr = wr * 128 + (p * 2 + ii) * 16 + lm;
#pragma unroll
        for (int kk = 0; kk < 2; ++kk)
          afrag[ii][kk] =
              *(const bf16x8*)(Ab + rr * 64 + (((kk << 2) + kg) ^ cxor) * 8);
      }
      if (p == 0) {
#pragma unroll
        for (int j = 0; j < 4; ++j) {
          const int rr = wc * 64 + j * 16 + lm;
#pragma unroll
          for (int kk = 0; kk < 2; ++kk)
            bfrag[j][kk] =
                *(const bf16x8*)(Bb + rr * 64 + (((kk << 2) + kg) ^ cxor) * 8);
        }
      }

      // ---- stage 1 half-tile prefetch ----
      // phases 0,1: A halves of tile t+1 -> other buffer (last read: t-1 ph3)
      // phases 2,3: B halves of tile t+2 -> this buffer (B consumed at ph0)
      if (p < 2) {
        if (t + 1 < NT)
          stage(A, arow + p * 128, (t + 1) * 64,
                &sm[buf ^ 1][0][p * 128 * 64]);
      } else {
        if (t + 2 < NT)
          stage(W, brow + (p - 2) * 128, (t + 2) * 64,
                &sm[buf][1][(p - 2) * 128 * 64]);
      }

      __builtin_amdgcn_s_barrier();
      asm volatile("s_waitcnt lgkmcnt(0)" ::: "memory");
      __builtin_amdgcn_sched_barrier(0);

      __builtin_amdgcn_s_setprio(1);
#pragma unroll
      for (int ii = 0; ii < 2; ++ii)
#pragma unroll
        for (int j = 0; j < 4; ++j)
#pragma unroll
          for (int kk = 0; kk < 2; ++kk)
            acc[p * 2 + ii][j] = __builtin_amdgcn_mfma_f32_16x16x32_bf16(
                afrag[ii][kk], bfrag[j][kk], acc[p * 2 + ii][j], 0, 0, 0);
      __builtin_amdgcn_s_setprio(0);

      if (p == 3) {
        // counted gate: <=4 outstanding (the 2 newest half-tiles) => all of
        // tile t+1 has landed before any wave reads it after this barrier.
        asm volatile("s_waitcnt vmcnt(4)" ::: "memory");
      }
      __builtin_amdgcn_s_barrier();
      if (p == 3) __builtin_amdgcn_sched_barrier(0);
    }
  }

  // ---- epilogue ----
#pragma unroll
  for (int i = 0; i < 8; ++i) {
    const int row0 = bm * 256 + wr * 128 + i * 16 + kg * 4;
#pragma unroll
    for (int j = 0; j < 4; ++j) {
      const int col = bn * 256 + wc * 64 + j * 16 + lm;
#pragma unroll
      for (int r = 0; r < 4; ++r) {
        if (CF32)
          ((float*)C)[(size_t)(row0 + r) * N + col] = acc[i][j][r];
        else
          ((unsigned short*)C)[(size_t)(row0 + r) * N + col] = f2bf(acc[i][j][r]);
      }
    }
  }
}

// ---------------------------------------------------------------------------
// MFMA-based per-token head-attention with fused RoPE (table-based).
// One wave per token (2 tokens / 128-thread block). Q/K/V staged as bf16
// rows [16][72] (b128 writes, conflict-free). Scores: S^T = K.Q^T via
// 2x mfma_16x16x32_bf16 -> s4[r] = S[lm][quad*4+r]. PV via mfma_16x16x16_bf16
// (P packed in-register; S^T C-layout == P A-layout) or lean VALU fallback.
// Output in transpose(0,2,1,3).reshape layout:
//   Y[b*8192 + qh*512 + t/16][(t&15)*64 + d]
// ---------------------------------------------------------------------------
#if defined(__has_builtin)
#if __has_builtin(__builtin_amdgcn_mfma_f32_16x16x16_bf16)
#define PV_MFMA 1
#define PV_MFMA_CALL(a, b, c) __builtin_amdgcn_mfma_f32_16x16x16_bf16( \
    *(bf16x4*)&(a), *(bf16x4*)&(b), (c), 0, 0, 0)
#elif __has_builtin(__builtin_amdgcn_mfma_f32_16x16x16bf16_1k)
#define PV_MFMA 1
#define PV_MFMA_CALL(a, b, c) __builtin_amdgcn_mfma_f32_16x16x16bf16_1k( \
    (a), (b), (c), 0, 0, 0)
#else
#define PV_MFMA 0
#endif
#else
#define PV_MFMA 0
#endif

__global__ __launch_bounds__(128) void attn_rope_k(
    const unsigned short* __restrict__ qkv,   // chunk-local, MCH tokens
    const float2* __restrict__ tab,
    unsigned short* __restrict__ Y,
    int base)
{
  // per-wave: Q [16][72], K [16][72], V [16][72] bf16 (pad 8 per row)
  __shared__ __align__(16) unsigned short sQKV[2][3 * 16 * 72];
#if !PV_MFMA
  __shared__ float sP[2][256];
#endif

  const int wave = threadIdx.x >> 6;
  const int lane = threadIdx.x & 63;
  const int ml = blockIdx.x * 2 + wave;  // chunk-local token
  const int m  = base + ml;              // global token
  const int t  = m & (TT - 1);
  const int b  = m >> 13;

  unsigned short* QB = sQKV[wave];            // Q rows
  unsigned short* KB = QB + 16 * 72;          // K rows
  unsigned short* VB = QB + 2 * 16 * 72;      // V rows

  const int lm   = lane & 15;
  const int quad = lane >> 4;

  // ---- staging: 6 x (b128 global read -> rope -> b128 LDS write) ----
  const uint4* row = (const uint4*)(qkv + (size_t)ml * 3072);
#pragma unroll
  for (int i = 0; i < 6; ++i) {
    const int c = lane + 64 * i;          // chunk of 8 bf16
    union { uint4 u4; unsigned short s[8]; } cv;
    cv.u4 = row[c];
    const int n0   = c * 8;
    const int part = n0 >> 10;            // 0=q 1=k 2=v (uniform per i)
    const int h    = (n0 >> 6) & 15;
    const int d0   = n0 & 63;
    if (part < 2) {
      float f[8];
#pragma unroll
      for (int j = 0; j < 8; ++j) f[j] = bf2f(cv.s[j]);
      const int p0 = d0 >> 1;
      const float4 csA = *(const float4*)(tab + (t << 5) + p0);
      const float4 csB = *(const float4*)(tab + (t << 5) + p0 + 2);
      const float cs[4] = {csA.x, csA.z, csB.x, csB.z};
      const float sn[4] = {csA.y, csA.w, csB.y, csB.w};
#pragma unroll
      for (int j = 0; j < 4; ++j) {
        const float x1 = f[2 * j], x2 = f[2 * j + 1];
        cv.s[2 * j]     = f2bf(x1 * cs[j] - x2 * sn[j]);
        cv.s[2 * j + 1] = f2bf(x2 * cs[j] + x1 * sn[j]);
      }
    }
    unsigned short* dst = QB + part * (16 * 72) + h * 72 + d0;
    *(uint4*)dst = cv.u4;
  }
  __syncthreads();

  // ---- scores: S^T = K . Q^T via 2x mfma_16x16x32 ----
  floatx4 accS = {0.f, 0.f, 0.f, 0.f};
#pragma unroll
  for (int half = 0; half < 2; ++half) {
    const bf16x8 kf = *(const bf16x8*)(KB + lm * 72 + half * 32 + quad * 8);
    const bf16x8 qf = *(const bf16x8*)(QB + lm * 72 + half * 32 + quad * 8);
    accS = __builtin_amdgcn_mfma_f32_16x16x32_bf16(kf, qf, accS, 0, 0, 0);
  }
  // accS[r] = S[q=lm][k=quad*4+r]
  float s4[4];
  float mx = -1e30f;
#pragma unroll
  for (int j = 0; j < 4; ++j) { s4[j] = accS[j] * 0.125f; mx = fmaxf(mx, s4[j]); }
  mx = fmaxf(mx, __shfl_xor(mx, 16, 64));
  mx = fmaxf(mx, __shfl_xor(mx, 32, 64));
  float sum = 0.f;
#pragma unroll
  for (int j = 0; j < 4; ++j) { s4[j] = __expf(s4[j] - mx); sum += s4[j]; }
  sum += __shfl_xor(sum, 16, 64);
  sum += __shfl_xor(sum, 32, 64);
  const float inv = 1.0f / sum;

#if PV_MFMA
  // ---- PV via mfma_16x16x16: A = P (in-register, S^T C-layout == A-layout)
  union { short4v v; unsigned short s[4]; } pf;
#pragma unroll
  for (int j = 0; j < 4; ++j) pf.s[j] = s4[j] * inv == 0.f ? 0 : f2bf(s4[j] * inv);
  // O[q=quad*4+r][dtile*16+lm]
#pragma unroll
  for (int dtile = 0; dtile < 4; ++dtile) {
    union { short4v v; unsigned short s[4]; } vf;
#pragma unroll
    for (int j = 0; j < 4; ++j)
      vf.s[j] = VB[(quad * 4 + j) * 72 + dtile * 16 + lm];
    floatx4 accO = {0.f, 0.f, 0.f, 0.f};
    accO = PV_MFMA_CALL(pf.v, vf.v, accO);
    const int col = (t & 15) * 64 + dtile * 16 + lm;
#pragma unroll
    for (int r = 0; r < 4; ++r) {
      const size_t rr = (size_t)b * TT + (size_t)(quad * 4 + r) * 512 + (t >> 4);
      Y[rr * 1024 + col] = f2bf(accO[r]);
    }
  }
#else
  // ---- VALU fallback: P via small LDS, V read as bf16 b128 ----
  float* P = sP[wave];
#pragma unroll
  for (int j = 0; j < 4; ++j) P[(quad * 4 + j) * 16 + lm] = s4[j] * inv;
  __syncthreads();
  float o[16];
#pragma unroll
  for (int dd = 0; dd < 16; ++dd) o[dd] = 0.f;
#pragma unroll
  for (int kh = 0; kh < 16; ++kh) {
    const float a = P[kh * 16 + lm];
    union { uint4 u4; unsigned short s[8]; } v0, v1;
    v0.u4 = *(const uint4*)(VB + kh * 72 + quad * 16);
    v1.u4 = *(const uint4*)(VB + kh * 72 + quad * 16 + 8);
#pragma unroll
    for (int dd = 0; dd < 8; ++dd) {
      o[dd]     += a * bf2f(v0.s[dd]);
      o[dd + 8] += a * bf2f(v1.s[dd]);
    }
  }
  const size_t rr = (size_t)b * TT + (size_t)lm * 512 + (t >> 4);
  unsigned short* yp = Y + rr * 1024 + (t & 15) * 64 + quad * 16;
  union { uint4 u4; unsigned short s[8]; } o1, o2;
#pragma unroll
  for (int dd = 0; dd < 8; ++dd) o1.s[dd] = f2bf(o[dd]);
#pragma unroll
  for (int dd = 0; dd < 8; ++dd) o2.s[dd] = f2bf(o[8 + dd]);
  ((uint4*)yp)[0] = o1.u4;
  ((uint4*)yp)[1] = o2.u4;
#endif
}

// ---------------------------------------------------------------------------
extern "C" void kernel_launch(void* const* d_in, const int* in_sizes, int n_in,
                              void* d_out, int out_size, void* d_ws, size_t ws_size,
                              hipStream_t stream) {
  const float* x    = (const float*)d_in[0];  // (2,8192,1024) fp32
  const float* Wqkv = (const float*)d_in[1];  // (3072,1024)  fp32
  const float* Wout = (const float*)d_in[2];  // (1024,1024)  fp32
  float* out = (float*)d_out;                 // (2,8192,1024) fp32

  // ws (56 MiB, proven): Y 32 | Wqkvb 6 | Woutb 2 | xb 16
  // d_out (67.1 MB): qkv chunk 50.3 MB at 0, rope table 2 MiB at +52 MiB.
  unsigned short* Y     = (unsigned short*)d_ws;
  unsigned short* Wqkvb = Y + (size_t)BT * 1024;
  unsigned short* Woutb = Wqkvb + (size_t)3072 * 1024;
  unsigned short* xb    = Woutb + (size_t)1024 * 1024;
  unsigned short* qkvC  = (unsigned short*)d_out;
  float2* tab           = (float2*)((char*)d_out + (size_t)52 * 1024 * 1024);

  rope_table_k<<<dim3(TT * 32 / 256), dim3(256), 0, stream>>>(tab);
  cvt_f2b<<<dim3(3072 * 1024 / 4 / 256), dim3(256), 0, stream>>>(Wqkv, Wqkvb, 3072 * 1024 / 4);
  cvt_f2b<<<dim3(1024 * 1024 / 4 / 256), dim3(256), 0, stream>>>(Wout, Woutb, 1024 * 1024 / 4);

  for (int base = 0; base < BT; base += MCH) {
    cvt_f2b<<<dim3(MCH * 1024 / 4 / 256), dim3(256), 0, stream>>>(
        x + (size_t)base * 1024, xb, MCH * 1024 / 4);
    gemm256<false><<<dim3((MCH / 256) * (3072 / 256)), dim3(512), 0, stream>>>(
        xb, Wqkvb, qkvC, MCH, 3072, 1024);
    attn_rope_k<<<dim3(MCH / 2), dim3(128), 0, stream>>>(qkvC, tab, Y, base);
  }

  // out = Y @ Wout^T : M=16384, N=1024, K=1024 (fp32 output)
  gemm256<true><<<dim3((BT / 256) * (1024 / 256)), dim3(512), 0, stream>>>(
      Y, Woutb, out, BT, 1024, 1024);
}

// Round 2
// 311.711 us; speedup vs baseline: 1.1463x; 1.0327x over previous
//
#include <hip/hip_runtime.h>
#include <stdint.h>

#define TT 8192          // sequence length T
#define BT 16384         // B*T tokens
#define MCH 8192         // token chunk for qkv GEMM + attention

typedef __attribute__((ext_vector_type(8))) __bf16 bf16x8;
typedef __attribute__((ext_vector_type(4))) __bf16 bf16x4;
typedef __attribute__((ext_vector_type(4))) short short4v;
typedef __attribute__((ext_vector_type(4))) float floatx4;

__device__ __forceinline__ float bf2f(unsigned short h) {
  union { unsigned u; float f; } x; x.u = ((unsigned)h) << 16; return x.f;
}
__device__ __forceinline__ unsigned short f2bf(float f) {
  union { float f; unsigned u; } x; x.f = f;
  unsigned r = (x.u + 0x7fffu + ((x.u >> 16) & 1u)) >> 16;
  return (unsigned short)r;
}
__device__ __forceinline__ void async16(const void* g, void* l) {
  __builtin_amdgcn_global_load_lds(
      (__attribute__((address_space(1))) void*)g,
      (__attribute__((address_space(3))) void*)l, 16, 0, 0);
}

// ---------------------------------------------------------------------------
// fp32 -> bf16 conversion (round-to-nearest-even), float4 vectorized.
// ---------------------------------------------------------------------------
__global__ __launch_bounds__(256) void cvt_f2b(
    const float* __restrict__ src, unsigned short* __restrict__ dst, int n4) {
  const int i = blockIdx.x * 256 + threadIdx.x;
  if (i < n4) {
    const float4 f = ((const float4*)src)[i];
    union { uint2 u2; unsigned short s[4]; } o;
    o.s[0] = f2bf(f.x); o.s[1] = f2bf(f.y);
    o.s[2] = f2bf(f.z); o.s[3] = f2bf(f.w);
    ((uint2*)dst)[i] = o.u2;
  }
}

// ---------------------------------------------------------------------------
// RoPE cos/sin table: tab[t*32+p] = (cos, sin) of t * 10000^(-p/32)
// ---------------------------------------------------------------------------
__global__ __launch_bounds__(256) void rope_table_k(float2* __restrict__ tab) {
  const int i = blockIdx.x * 256 + threadIdx.x;
  if (i < TT * 32) {
    const int t = i >> 5, p = i & 31;
    const float f = (float)t * exp2f((float)p * -0.41524101186092f); // -log2(1e4)/32
    float s, c;
    sincosf(f, &s, &c);
    tab[i] = make_float2(c, s);
  }
}

// ---------------------------------------------------------------------------
// GEMM, occupancy-first pipelined schedule: C[M,N] = A[M,K] . W[N,K]^T
// BM=256, BN=128, BK=32, 8 waves (4M x 2N), wave-tile 64x64 (acc[4][4]),
// LDS 48 KiB double-buffered -> 2 blocks/CU (16 waves/CU) with
// __launch_bounds__(512,4) capping VGPR<=128. One phase per K-tile:
// {8x ds_read_b128 -> barrier -> lgkmcnt(0) -> stage(t+2, 3x gload_lds)
//  -> setprio(1) 16x MFMA setprio(0) -> vmcnt(3) -> barrier}.
// Counted vmcnt(3) keeps the next tile's loads in flight across barriers.
// XOR swizzle chunk ^= (row>>1)&3 on both stage-source and ds_read addr
// (bank-quad (row&1)*4 + chunk^((row>>1)&3) is bijective per 8 rows ->
// free 2-way aliasing, no conflicts). XCD-aware blockIdx swizzle.
// Requires: M%256==0, N%128==0, K%32==0, K/32>=2, grid%8==0.
// ---------------------------------------------------------------------------
template <bool CF32>
__global__ __launch_bounds__(512, 4) void gemm_k32(
    const unsigned short* __restrict__ A,
    const unsigned short* __restrict__ W,
    void* __restrict__ C,
    int M, int N, int K)
{
  // per buf: A [256][32] (16 KB) + B [128][32] (8 KB) = 24 KB; x2 = 48 KiB
  __shared__ __align__(16) unsigned short sm[2][(256 + 128) * 32];

  const int tid  = threadIdx.x;
  const int lane = tid & 63;
  const int wid  = tid >> 6;
  const int wr   = wid >> 1;          // 0..3 : wave row (M, 64 rows each)
  const int wc   = wid & 1;           // 0..1 : wave col (N, 64 cols each)
  const int lm   = lane & 15;
  const int kg   = lane >> 4;
  const int cxor = (lm >> 1) & 3;     // read-side swizzle term ((row>>1)&3)

  // XCD-aware swizzle (grid % 8 == 0 for both call sites -> bijective)
  const int nb  = N >> 7;
  const int cpx = (int)gridDim.x >> 3;
  const int bid = blockIdx.x;
  const int swz = (bid & 7) * cpx + (bid >> 3);
  const int bm  = swz / nb;
  const int bn  = swz % nb;

  const int NT = K >> 5;              // K-tiles of 32

  // ---- staging geometry: 3 x global_load_lds(16B) per wave per tile ----
  // call q in {0,1}: A rows q*128 + wid*16 + lane/4 ; call 2: B rows.
  // LDS dest linear (wave-uniform base + lane*16): row = .., chunk = lane&3.
  // Global source chunk pre-swizzled: c = (lane&3) ^ ((row>>1)&3).
  const int sr  = lane >> 2;
  const int scb = lane & 3;
  const unsigned short* gsrc0;
  const unsigned short* gsrc1;
  const unsigned short* gsrc2;
  {
    const int r0 = wid * 16 + sr;          // 0..127
    const int r1 = 128 + r0;               // 128..255
    const int rB = wid * 16 + sr;          // 0..127
    gsrc0 = A + (size_t)(bm * 256 + r0) * (size_t)K + ((scb ^ ((r0 >> 1) & 3)) << 3);
    gsrc1 = A + (size_t)(bm * 256 + r1) * (size_t)K + ((scb ^ ((r1 >> 1) & 3)) << 3);
    gsrc2 = W + (size_t)(bn * 128 + rB) * (size_t)K + ((scb ^ ((rB >> 1) & 3)) << 3);
  }
  const int ld0 = wid * 1024;              // A half 0
  const int ld1 = 8192 + wid * 1024;       // A half 1
  const int ld2 = 16384 + wid * 1024;      // B

  auto stage_tile = [&](int tt) {
    char* lb = (char*)sm[tt & 1];
    const size_t koff = (size_t)tt << 5;   // element offset along K
    async16(gsrc0 + koff, lb + ld0);
    async16(gsrc1 + koff, lb + ld1);
    async16(gsrc2 + koff, lb + ld2);
  };

  floatx4 acc[4][4];
  floatx4 z = {0.f, 0.f, 0.f, 0.f};
#pragma unroll
  for (int i = 0; i < 4; ++i)
#pragma unroll
    for (int j = 0; j < 4; ++j) acc[i][j] = z;

  // ---- prologue: tiles 0 and 1 in flight; gate on tile-0 residency ----
  stage_tile(0);
  stage_tile(1);
  asm volatile("s_waitcnt vmcnt(3)" ::: "memory");
  __builtin_amdgcn_s_barrier();
  __builtin_amdgcn_sched_barrier(0);

  for (int t = 0; t < NT; ++t) {
    const unsigned short* Ab = sm[t & 1];
    const unsigned short* Bb = Ab + 256 * 32;

    bf16x8 af[4], bfr[4];
#pragma unroll
    for (int i = 0; i < 4; ++i) {
      const int rr = wr * 64 + i * 16 + lm;
      af[i] = *(const bf16x8*)(Ab + rr * 32 + ((kg ^ cxor) << 3));
    }
#pragma unroll
    for (int j = 0; j < 4; ++j) {
      const int rr = wc * 64 + j * 16 + lm;
      bfr[j] = *(const bf16x8*)(Bb + rr * 32 + ((kg ^ cxor) << 3));
    }

    // all waves' reads of this tile issued before anyone overwrites the buf
    __builtin_amdgcn_s_barrier();
    asm volatile("s_waitcnt lgkmcnt(0)" ::: "memory");
    __builtin_amdgcn_sched_barrier(0);

    if (t + 2 < NT) stage_tile(t + 2);   // overwrites buf just consumed

    __builtin_amdgcn_s_setprio(1);
#pragma unroll
    for (int i = 0; i < 4; ++i)
#pragma unroll
      for (int j = 0; j < 4; ++j)
        acc[i][j] = __builtin_amdgcn_mfma_f32_16x16x32_bf16(
            af[i], bfr[j], acc[i][j], 0, 0, 0);
    __builtin_amdgcn_s_setprio(0);

    if (t + 1 < NT) {
      // gate: tile t+1 resident; tile t+2's 3 loads may stay in flight.
      if (t + 2 < NT)
        asm volatile("s_waitcnt vmcnt(3)" ::: "memory");
      else
        asm volatile("s_waitcnt vmcnt(0)" ::: "memory");
      __builtin_amdgcn_s_barrier();
      __builtin_amdgcn_sched_barrier(0);
    }
  }

  // ---- epilogue ----
#pragma unroll
  for (int i = 0; i < 4; ++i) {
    const int row0 = bm * 256 + wr * 64 + i * 16 + kg * 4;
#pragma unroll
    for (int j = 0; j < 4; ++j) {
      const int col = bn * 128 + wc * 64 + j * 16 + lm;
#pragma unroll
      for (int r = 0; r < 4; ++r) {
        if (CF32)
          ((float*)C)[(size_t)(row0 + r) * N + col] = acc[i][j][r];
        else
          ((unsigned short*)C)[(size_t)(row0 + r) * N + col] = f2bf(acc[i][j][r]);
      }
    }
  }
}

// ---------------------------------------------------------------------------
// MFMA-based per-token head-attention with fused RoPE (table-based).
// One wave per token (2 tokens / 128-thread block). Q/K/V staged as bf16
// rows [16][72] (b128 writes, conflict-free). Scores: S^T = K.Q^T via
// 2x mfma_16x16x32_bf16 -> s4[r] = S[lm][quad*4+r]. PV via mfma_16x16x16_bf16
// (P packed in-register; S^T C-layout == P A-layout) or lean VALU fallback.
// Output in transpose(0,2,1,3).reshape layout:
//   Y[b*8192 + qh*512 + t/16][(t&15)*64 + d]
// ---------------------------------------------------------------------------
#if defined(__has_builtin)
#if __has_builtin(__builtin_amdgcn_mfma_f32_16x16x16_bf16)
#define PV_MFMA 1
#define PV_MFMA_CALL(a, b, c) __builtin_amdgcn_mfma_f32_16x16x16_bf16( \
    *(bf16x4*)&(a), *(bf16x4*)&(b), (c), 0, 0, 0)
#elif __has_builtin(__builtin_amdgcn_mfma_f32_16x16x16bf16_1k)
#define PV_MFMA 1
#define PV_MFMA_CALL(a, b, c) __builtin_amdgcn_mfma_f32_16x16x16bf16_1k( \
    (a), (b), (c), 0, 0, 0)
#else
#define PV_MFMA 0
#endif
#else
#define PV_MFMA 0
#endif

__global__ __launch_bounds__(128) void attn_rope_k(
    const unsigned short* __restrict__ qkv,   // chunk-local, MCH tokens
    const float2* __restrict__ tab,
    unsigned short* __restrict__ Y,
    int base)
{
  // per-wave: Q [16][72], K [16][72], V [16][72] bf16 (pad 8 per row)
  __shared__ __align__(16) unsigned short sQKV[2][3 * 16 * 72];
#if !PV_MFMA
  __shared__ float sP[2][256];
#endif

  const int wave = threadIdx.x >> 6;
  const int lane = threadIdx.x & 63;
  const int ml = blockIdx.x * 2 + wave;  // chunk-local token
  const int m  = base + ml;              // global token
  const int t  = m & (TT - 1);
  const int b  = m >> 13;

  unsigned short* QB = sQKV[wave];            // Q rows
  unsigned short* KB = QB + 16 * 72;          // K rows
  unsigned short* VB = QB + 2 * 16 * 72;      // V rows

  const int lm   = lane & 15;
  const int quad = lane >> 4;

  // ---- staging: 6 x (b128 global read -> rope -> b128 LDS write) ----
  const uint4* row = (const uint4*)(qkv + (size_t)ml * 3072);
#pragma unroll
  for (int i = 0; i < 6; ++i) {
    const int c = lane + 64 * i;          // chunk of 8 bf16
    union { uint4 u4; unsigned short s[8]; } cv;
    cv.u4 = row[c];
    const int n0   = c * 8;
    const int part = n0 >> 10;            // 0=q 1=k 2=v (uniform per i)
    const int h    = (n0 >> 6) & 15;
    const int d0   = n0 & 63;
    if (part < 2) {
      float f[8];
#pragma unroll
      for (int j = 0; j < 8; ++j) f[j] = bf2f(cv.s[j]);
      const int p0 = d0 >> 1;
      const float4 csA = *(const float4*)(tab + (t << 5) + p0);
      const float4 csB = *(const float4*)(tab + (t << 5) + p0 + 2);
      const float cs[4] = {csA.x, csA.z, csB.x, csB.z};
      const float sn[4] = {csA.y, csA.w, csB.y, csB.w};
#pragma unroll
      for (int j = 0; j < 4; ++j) {
        const float x1 = f[2 * j], x2 = f[2 * j + 1];
        cv.s[2 * j]     = f2bf(x1 * cs[j] - x2 * sn[j]);
        cv.s[2 * j + 1] = f2bf(x2 * cs[j] + x1 * sn[j]);
      }
    }
    unsigned short* dst = QB + part * (16 * 72) + h * 72 + d0;
    *(uint4*)dst = cv.u4;
  }
  __syncthreads();

  // ---- scores: S^T = K . Q^T via 2x mfma_16x16x32 ----
  floatx4 accS = {0.f, 0.f, 0.f, 0.f};
#pragma unroll
  for (int half = 0; half < 2; ++half) {
    const bf16x8 kf = *(const bf16x8*)(KB + lm * 72 + half * 32 + quad * 8);
    const bf16x8 qf = *(const bf16x8*)(QB + lm * 72 + half * 32 + quad * 8);
    accS = __builtin_amdgcn_mfma_f32_16x16x32_bf16(kf, qf, accS, 0, 0, 0);
  }
  // accS[r] = S[q=lm][k=quad*4+r]
  float s4[4];
  float mx = -1e30f;
#pragma unroll
  for (int j = 0; j < 4; ++j) { s4[j] = accS[j] * 0.125f; mx = fmaxf(mx, s4[j]); }
  mx = fmaxf(mx, __shfl_xor(mx, 16, 64));
  mx = fmaxf(mx, __shfl_xor(mx, 32, 64));
  float sum = 0.f;
#pragma unroll
  for (int j = 0; j < 4; ++j) { s4[j] = __expf(s4[j] - mx); sum += s4[j]; }
  sum += __shfl_xor(sum, 16, 64);
  sum += __shfl_xor(sum, 32, 64);
  const float inv = 1.0f / sum;

#if PV_MFMA
  // ---- PV via mfma_16x16x16: A = P (in-register, S^T C-layout == A-layout)
  union { short4v v; unsigned short s[4]; } pf;
#pragma unroll
  for (int j = 0; j < 4; ++j) pf.s[j] = s4[j] * inv == 0.f ? 0 : f2bf(s4[j] * inv);
  // O[q=quad*4+r][dtile*16+lm]
#pragma unroll
  for (int dtile = 0; dtile < 4; ++dtile) {
    union { short4v v; unsigned short s[4]; } vf;
#pragma unroll
    for (int j = 0; j < 4; ++j)
      vf.s[j] = VB[(quad * 4 + j) * 72 + dtile * 16 + lm];
    floatx4 accO = {0.f, 0.f, 0.f, 0.f};
    accO = PV_MFMA_CALL(pf.v, vf.v, accO);
    const int col = (t & 15) * 64 + dtile * 16 + lm;
#pragma unroll
    for (int r = 0; r < 4; ++r) {
      const size_t rr = (size_t)b * TT + (size_t)(quad * 4 + r) * 512 + (t >> 4);
      Y[rr * 1024 + col] = f2bf(accO[r]);
    }
  }
#else
  // ---- VALU fallback: P via small LDS, V read as bf16 b128 ----
  float* P = sP[wave];
#pragma unroll
  for (int j = 0; j < 4; ++j) P[(quad * 4 + j) * 16 + lm] = s4[j] * inv;
  __syncthreads();
  float o[16];
#pragma unroll
  for (int dd = 0; dd < 16; ++dd) o[dd] = 0.f;
#pragma unroll
  for (int kh = 0; kh < 16; ++kh) {
    const float a = P[kh * 16 + lm];
    union { uint4 u4; unsigned short s[8]; } v0, v1;
    v0.u4 = *(const uint4*)(VB + kh * 72 + quad * 16);
    v1.u4 = *(const uint4*)(VB + kh * 72 + quad * 16 + 8);
#pragma unroll
    for (int dd = 0; dd < 8; ++dd) {
      o[dd]     += a * bf2f(v0.s[dd]);
      o[dd + 8] += a * bf2f(v1.s[dd]);
    }
  }
  const size_t rr = (size_t)b * TT + (size_t)lm * 512 + (t >> 4);
  unsigned short* yp = Y + rr * 1024 + (t & 15) * 64 + quad * 16;
  union { uint4 u4; unsigned short s[8]; } o1, o2;
#pragma unroll
  for (int dd = 0; dd < 8; ++dd) o1.s[dd] = f2bf(o[dd]);
#pragma unroll
  for (int dd = 0; dd < 8; ++dd) o2.s[dd] = f2bf(o[8 + dd]);
  ((uint4*)yp)[0] = o1.u4;
  ((uint4*)yp)[1] = o2.u4;
#endif
}

// ---------------------------------------------------------------------------
extern "C" void kernel_launch(void* const* d_in, const int* in_sizes, int n_in,
                              void* d_out, int out_size, void* d_ws, size_t ws_size,
                              hipStream_t stream) {
  const float* x    = (const float*)d_in[0];  // (2,8192,1024) fp32
  const float* Wqkv = (const float*)d_in[1];  // (3072,1024)  fp32
  const float* Wout = (const float*)d_in[2];  // (1024,1024)  fp32
  float* out = (float*)d_out;                 // (2,8192,1024) fp32

  // ws (56 MiB, proven): Y 32 | Wqkvb 6 | Woutb 2 | xb 16
  // d_out (67.1 MB): qkv chunk 50.3 MB at 0, rope table 2 MiB at +52 MiB.
  unsigned short* Y     = (unsigned short*)d_ws;
  unsigned short* Wqkvb = Y + (size_t)BT * 1024;
  unsigned short* Woutb = Wqkvb + (size_t)3072 * 1024;
  unsigned short* xb    = Woutb + (size_t)1024 * 1024;
  unsigned short* qkvC  = (unsigned short*)d_out;
  float2* tab           = (float2*)((char*)d_out + (size_t)52 * 1024 * 1024);

  rope_table_k<<<dim3(TT * 32 / 256), dim3(256), 0, stream>>>(tab);
  cvt_f2b<<<dim3(3072 * 1024 / 4 / 256), dim3(256), 0, stream>>>(Wqkv, Wqkvb, 3072 * 1024 / 4);
  cvt_f2b<<<dim3(1024 * 1024 / 4 / 256), dim3(256), 0, stream>>>(Wout, Woutb, 1024 * 1024 / 4);

  for (int base = 0; base < BT; base += MCH) {
    cvt_f2b<<<dim3(MCH * 1024 / 4 / 256), dim3(256), 0, stream>>>(
        x + (size_t)base * 1024, xb, MCH * 1024 / 4);
    gemm_k32<false><<<dim3((MCH / 256) * (3072 / 128)), dim3(512), 0, stream>>>(
        xb, Wqkvb, qkvC, MCH, 3072, 1024);
    attn_rope_k<<<dim3(MCH / 2), dim3(128), 0, stream>>>(qkvC, tab, Y, base);
  }

  // out = Y @ Wout^T : M=16384, N=1024, K=1024 (fp32 output)
  gemm_k32<true><<<dim3((BT / 256) * (1024 / 128)), dim3(512), 0, stream>>>(
      Y, Woutb, out, BT, 1024, 1024);
}

// Round 3
// 307.506 us; speedup vs baseline: 1.1620x; 1.0137x over previous
//
#include <hip/hip_runtime.h>
#include <stdint.h>

#define TT 8192          // sequence length T
#define BT 16384         // B*T tokens
#define MCH 8192         // token chunk for qkv GEMM + attention

typedef __attribute__((ext_vector_type(8))) __bf16 bf16x8;
typedef __attribute__((ext_vector_type(4))) __bf16 bf16x4;
typedef __attribute__((ext_vector_type(4))) short short4v;
typedef __attribute__((ext_vector_type(4))) float floatx4;

__device__ __forceinline__ float bf2f(unsigned short h) {
  union { unsigned u; float f; } x; x.u = ((unsigned)h) << 16; return x.f;
}
__device__ __forceinline__ unsigned short f2bf(float f) {
  union { float f; unsigned u; } x; x.f = f;
  unsigned r = (x.u + 0x7fffu + ((x.u >> 16) & 1u)) >> 16;
  return (unsigned short)r;
}
__device__ __forceinline__ void async16(const void* g, void* l) {
  __builtin_amdgcn_global_load_lds(
      (__attribute__((address_space(1))) void*)g,
      (__attribute__((address_space(3))) void*)l, 16, 0, 0);
}

// ---------------------------------------------------------------------------
// fp32 -> bf16 conversion (round-to-nearest-even), float4 vectorized.
// ---------------------------------------------------------------------------
__global__ __launch_bounds__(256) void cvt_f2b(
    const float* __restrict__ src, unsigned short* __restrict__ dst, int n4) {
  const int i = blockIdx.x * 256 + threadIdx.x;
  if (i < n4) {
    const float4 f = ((const float4*)src)[i];
    union { uint2 u2; unsigned short s[4]; } o;
    o.s[0] = f2bf(f.x); o.s[1] = f2bf(f.y);
    o.s[2] = f2bf(f.z); o.s[3] = f2bf(f.w);
    ((uint2*)dst)[i] = o.u2;
  }
}

// ---------------------------------------------------------------------------
// RoPE cos/sin table: tab[t*32+p] = (cos, sin) of t * 10000^(-p/32)
// ---------------------------------------------------------------------------
__global__ __launch_bounds__(256) void rope_table_k(float2* __restrict__ tab) {
  const int i = blockIdx.x * 256 + threadIdx.x;
  if (i < TT * 32) {
    const int t = i >> 5, p = i & 31;
    const float f = (float)t * exp2f((float)p * -0.41524101186092f); // -log2(1e4)/32
    float s, c;
    sincosf(f, &s, &c);
    tab[i] = make_float2(c, s);
  }
}

// ---------------------------------------------------------------------------
// GEMM, register-double-buffered 3-deep pipeline: C[M,N] = A[M,K] . W[N,K]^T
// BM=256, BN=128, BK=32; 4 waves (2M x 2N), wave-tile 128x64, acc[8][4] AGPR.
// 3 rotating LDS buffers (72 KiB), staging 3 tiles ahead via global_load_lds
// (6 x 16B per wave per tile), gated by counted vmcnt(6) (never 0 mid-loop).
// A-fragments for tile t+1 are ds_read BEFORE MFMA(t) and waited one iter
// later with counted lgkmcnt(8); sched_barrier(0) pins B-read/A-read issue
// order so the 8 newest lgkm ops are provably the A reads. B-fragments are
// read just-in-time (covered by the same gate). XOR chunk-swizzle
// (chunk ^= (row>>1)&3) on stage-source and read addr (0 conflicts, r2).
// 2 blocks/CU (8 waves): __launch_bounds__(256,2), VGPR+AGPR ~240 <= 256.
// Requires: M%256==0, N%128==0, K%32==0, K/32>=4 even, grid%8==0.
// ---------------------------------------------------------------------------
template <bool CF32>
__global__ __launch_bounds__(256, 2) void gemm_p3(
    const unsigned short* __restrict__ A,
    const unsigned short* __restrict__ W,
    void* __restrict__ C,
    int M, int N, int K)
{
  // per buffer: A [256][32] (16 KB) + B [128][32] (8 KB) = 24 KB; x3 = 72 KiB
  __shared__ __align__(16) unsigned short sm[3][(256 + 128) * 32];

  const int tid  = threadIdx.x;
  const int lane = tid & 63;
  const int wid  = tid >> 6;          // 0..3
  const int wr   = wid >> 1;          // 0..1 : wave row (M, 128 rows)
  const int wc   = wid & 1;           // 0..1 : wave col (N, 64 cols)
  const int lm   = lane & 15;
  const int kg   = lane >> 4;
  const int cxor = (lm >> 1) & 3;     // read-side swizzle term ((row>>1)&3)

  // XCD-aware swizzle (grid % 8 == 0 for both call sites -> bijective)
  const int nb  = N >> 7;
  const int cpx = (int)gridDim.x >> 3;
  const int bid = blockIdx.x;
  const int swz = (bid & 7) * cpx + (bid >> 3);
  const int bm  = swz / nb;
  const int bn  = swz % nb;

  const int NT = K >> 5;              // K-tiles of 32

  // ---- staging sources: 6 x global_load_lds(16B) per wave per tile ----
  // A: 16 segments of 16 rows (wave w: segs 4w..4w+3); B: 8 segs (2w..2w+1).
  // LDS dest linear (uniform base + lane*16); source chunk pre-swizzled.
  const int sr  = lane >> 2;
  const int scb = lane & 3;
  const unsigned short* gA[4];
  const unsigned short* gB[2];
#pragma unroll
  for (int q = 0; q < 4; ++q) {
    const int r = (wid * 4 + q) * 16 + sr;       // 0..255
    gA[q] = A + (size_t)(bm * 256 + r) * (size_t)K + ((scb ^ ((r >> 1) & 3)) << 3);
  }
#pragma unroll
  for (int q = 0; q < 2; ++q) {
    const int r = (wid * 2 + q) * 16 + sr;       // 0..127
    gB[q] = W + (size_t)(bn * 128 + r) * (size_t)K + ((scb ^ ((r >> 1) & 3)) << 3);
  }

  auto stage_tile = [&](int tt, unsigned short* lb) {
    const size_t koff = (size_t)tt << 5;
    char* lc = (char*)lb;
#pragma unroll
    for (int q = 0; q < 4; ++q)
      async16(gA[q] + koff, lc + (wid * 4 + q) * 1024);
#pragma unroll
    for (int q = 0; q < 2; ++q)
      async16(gB[q] + koff, lc + 16384 + (wid * 2 + q) * 1024);
  };

  auto readA = [&](const unsigned short* buf, bf16x8* dst) {
#pragma unroll
    for (int i = 0; i < 8; ++i) {
      const int rr = wr * 128 + i * 16 + lm;
      dst[i] = *(const bf16x8*)(buf + rr * 32 + ((kg ^ cxor) << 3));
    }
  };
  auto readB = [&](const unsigned short* buf, bf16x8* dst) {
#pragma unroll
    for (int j = 0; j < 4; ++j) {
      const int rr = wc * 64 + j * 16 + lm;
      dst[j] = *(const bf16x8*)(buf + 256 * 32 + rr * 32 + ((kg ^ cxor) << 3));
    }
  };

  floatx4 acc[8][4];
  floatx4 z = {0.f, 0.f, 0.f, 0.f};
#pragma unroll
  for (int i = 0; i < 8; ++i)
#pragma unroll
    for (int j = 0; j < 4; ++j) acc[i][j] = z;

  unsigned short* b0 = sm[0];   // compute buffer (tile u)
  unsigned short* b1 = sm[1];   // next (tile u+1)
  unsigned short* b2 = sm[2];   // far (tile u+2)

  // ---- prologue: tiles 0,1,2 staged; gate tiles 0,1; preload A(0) ----
  stage_tile(0, b0);
  stage_tile(1, b1);
  stage_tile(2, b2);
  asm volatile("s_waitcnt vmcnt(6)" ::: "memory");   // tiles 0,1 resident
  __builtin_amdgcn_s_barrier();
  __builtin_amdgcn_sched_barrier(0);

  bf16x8 afA[8], afB[8], bfr[4];
  readA(b0, afA);

#define SUBITER(U, CUR, NXT)                                                  \
  {                                                                           \
    const int u_ = (U);                                                       \
    readB(b0, bfr);                                                           \
    __builtin_amdgcn_sched_barrier(0); /* pin order: B reads older than A */  \
    if (u_ + 1 < NT) {                                                        \
      readA(b1, NXT);                                                         \
      asm volatile("s_waitcnt lgkmcnt(8)" ::: "memory");                      \
    } else {                                                                  \
      asm volatile("s_waitcnt lgkmcnt(0)" ::: "memory");                      \
    }                                                                         \
    __builtin_amdgcn_sched_barrier(0);                                        \
    __builtin_amdgcn_s_barrier(); /* all waves done reading b0 */             \
    if (u_ + 3 < NT) stage_tile(u_ + 3, b0);                                  \
    __builtin_amdgcn_s_setprio(1);                                            \
    _Pragma("unroll")                                                         \
    for (int i = 0; i < 8; ++i)                                               \
      _Pragma("unroll")                                                       \
      for (int j = 0; j < 4; ++j)                                             \
        acc[i][j] = __builtin_amdgcn_mfma_f32_16x16x32_bf16(                  \
            CUR[i], bfr[j], acc[i][j], 0, 0, 0);                              \
    __builtin_amdgcn_s_setprio(0);                                            \
    if (u_ + 4 <= NT)                                                         \
      asm volatile("s_waitcnt vmcnt(6)" ::: "memory");                        \
    else                                                                      \
      asm volatile("s_waitcnt vmcnt(0)" ::: "memory");                        \
    __builtin_amdgcn_sched_barrier(0);                                        \
    __builtin_amdgcn_s_barrier();                                             \
    unsigned short* tmp_ = b0; b0 = b1; b1 = b2; b2 = tmp_;                   \
  }

  for (int u = 0; u < NT; u += 2) {
    SUBITER(u, afA, afB);
    SUBITER(u + 1, afB, afA);
  }
#undef SUBITER

  // ---- epilogue ----
#pragma unroll
  for (int i = 0; i < 8; ++i) {
    const int row0 = bm * 256 + wr * 128 + i * 16 + kg * 4;
#pragma unroll
    for (int j = 0; j < 4; ++j) {
      const int col = bn * 128 + wc * 64 + j * 16 + lm;
#pragma unroll
      for (int r = 0; r < 4; ++r) {
        if (CF32)
          ((float*)C)[(size_t)(row0 + r) * N + col] = acc[i][j][r];
        else
          ((unsigned short*)C)[(size_t)(row0 + r) * N + col] = f2bf(acc[i][j][r]);
      }
    }
  }
}

// ---------------------------------------------------------------------------
// MFMA-based per-token head-attention with fused RoPE (table-based).
// One wave per token (2 tokens / 128-thread block). Q/K/V staged as bf16
// rows [16][72] (b128 writes, conflict-free). Scores: S^T = K.Q^T via
// 2x mfma_16x16x32_bf16 -> s4[r] = S[lm][quad*4+r]. PV via mfma_16x16x16_bf16
// (P packed in-register; S^T C-layout == P A-layout) or lean VALU fallback.
// Output in transpose(0,2,1,3).reshape layout:
//   Y[b*8192 + qh*512 + t/16][(t&15)*64 + d]
// ---------------------------------------------------------------------------
#if defined(__has_builtin)
#if __has_builtin(__builtin_amdgcn_mfma_f32_16x16x16_bf16)
#define PV_MFMA 1
#define PV_MFMA_CALL(a, b, c) __builtin_amdgcn_mfma_f32_16x16x16_bf16( \
    *(bf16x4*)&(a), *(bf16x4*)&(b), (c), 0, 0, 0)
#elif __has_builtin(__builtin_amdgcn_mfma_f32_16x16x16bf16_1k)
#define PV_MFMA 1
#define PV_MFMA_CALL(a, b, c) __builtin_amdgcn_mfma_f32_16x16x16bf16_1k( \
    (a), (b), (c), 0, 0, 0)
#else
#define PV_MFMA 0
#endif
#else
#define PV_MFMA 0
#endif

__global__ __launch_bounds__(128) void attn_rope_k(
    const unsigned short* __restrict__ qkv,   // chunk-local, MCH tokens
    const float2* __restrict__ tab,
    unsigned short* __restrict__ Y,
    int base)
{
  // per-wave: Q [16][72], K [16][72], V [16][72] bf16 (pad 8 per row)
  __shared__ __align__(16) unsigned short sQKV[2][3 * 16 * 72];
#if !PV_MFMA
  __shared__ float sP[2][256];
#endif

  const int wave = threadIdx.x >> 6;
  const int lane = threadIdx.x & 63;
  const int ml = blockIdx.x * 2 + wave;  // chunk-local token
  const int m  = base + ml;              // global token
  const int t  = m & (TT - 1);
  const int b  = m >> 13;

  unsigned short* QB = sQKV[wave];            // Q rows
  unsigned short* KB = QB + 16 * 72;          // K rows
  unsigned short* VB = QB + 2 * 16 * 72;      // V rows

  const int lm   = lane & 15;
  const int quad = lane >> 4;

  // ---- staging: 6 x (b128 global read -> rope -> b128 LDS write) ----
  const uint4* row = (const uint4*)(qkv + (size_t)ml * 3072);
#pragma unroll
  for (int i = 0; i < 6; ++i) {
    const int c = lane + 64 * i;          // chunk of 8 bf16
    union { uint4 u4; unsigned short s[8]; } cv;
    cv.u4 = row[c];
    const int n0   = c * 8;
    const int part = n0 >> 10;            // 0=q 1=k 2=v (uniform per i)
    const int h    = (n0 >> 6) & 15;
    const int d0   = n0 & 63;
    if (part < 2) {
      float f[8];
#pragma unroll
      for (int j = 0; j < 8; ++j) f[j] = bf2f(cv.s[j]);
      const int p0 = d0 >> 1;
      const float4 csA = *(const float4*)(tab + (t << 5) + p0);
      const float4 csB = *(const float4*)(tab + (t << 5) + p0 + 2);
      const float cs[4] = {csA.x, csA.z, csB.x, csB.z};
      const float sn[4] = {csA.y, csA.w, csB.y, csB.w};
#pragma unroll
      for (int j = 0; j < 4; ++j) {
        const float x1 = f[2 * j], x2 = f[2 * j + 1];
        cv.s[2 * j]     = f2bf(x1 * cs[j] - x2 * sn[j]);
        cv.s[2 * j + 1] = f2bf(x2 * cs[j] + x1 * sn[j]);
      }
    }
    unsigned short* dst = QB + part * (16 * 72) + h * 72 + d0;
    *(uint4*)dst = cv.u4;
  }
  __syncthreads();

  // ---- scores: S^T = K . Q^T via 2x mfma_16x16x32 ----
  floatx4 accS = {0.f, 0.f, 0.f, 0.f};
#pragma unroll
  for (int half = 0; half < 2; ++half) {
    const bf16x8 kf = *(const bf16x8*)(KB + lm * 72 + half * 32 + quad * 8);
    const bf16x8 qf = *(const bf16x8*)(QB + lm * 72 + half * 32 + quad * 8);
    accS = __builtin_amdgcn_mfma_f32_16x16x32_bf16(kf, qf, accS, 0, 0, 0);
  }
  // accS[r] = S[q=lm][k=quad*4+r]
  float s4[4];
  float mx = -1e30f;
#pragma unroll
  for (int j = 0; j < 4; ++j) { s4[j] = accS[j] * 0.125f; mx = fmaxf(mx, s4[j]); }
  mx = fmaxf(mx, __shfl_xor(mx, 16, 64));
  mx = fmaxf(mx, __shfl_xor(mx, 32, 64));
  float sum = 0.f;
#pragma unroll
  for (int j = 0; j < 4; ++j) { s4[j] = __expf(s4[j] - mx); sum += s4[j]; }
  sum += __shfl_xor(sum, 16, 64);
  sum += __shfl_xor(sum, 32, 64);
  const float inv = 1.0f / sum;

#if PV_MFMA
  // ---- PV via mfma_16x16x16: A = P (in-register, S^T C-layout == A-layout)
  union { short4v v; unsigned short s[4]; } pf;
#pragma unroll
  for (int j = 0; j < 4; ++j) pf.s[j] = s4[j] * inv == 0.f ? 0 : f2bf(s4[j] * inv);
  // O[q=quad*4+r][dtile*16+lm]
#pragma unroll
  for (int dtile = 0; dtile < 4; ++dtile) {
    union { short4v v; unsigned short s[4]; } vf;
#pragma unroll
    for (int j = 0; j < 4; ++j)
      vf.s[j] = VB[(quad * 4 + j) * 72 + dtile * 16 + lm];
    floatx4 accO = {0.f, 0.f, 0.f, 0.f};
    accO = PV_MFMA_CALL(pf.v, vf.v, accO);
    const int col = (t & 15) * 64 + dtile * 16 + lm;
#pragma unroll
    for (int r = 0; r < 4; ++r) {
      const size_t rr = (size_t)b * TT + (size_t)(quad * 4 + r) * 512 + (t >> 4);
      Y[rr * 1024 + col] = f2bf(accO[r]);
    }
  }
#else
  // ---- VALU fallback: P via small LDS, V read as bf16 b128 ----
  float* P = sP[wave];
#pragma unroll
  for (int j = 0; j < 4; ++j) P[(quad * 4 + j) * 16 + lm] = s4[j] * inv;
  __syncthreads();
  float o[16];
#pragma unroll
  for (int dd = 0; dd < 16; ++dd) o[dd] = 0.f;
#pragma unroll
  for (int kh = 0; kh < 16; ++kh) {
    const float a = P[kh * 16 + lm];
    union { uint4 u4; unsigned short s[8]; } v0, v1;
    v0.u4 = *(const uint4*)(VB + kh * 72 + quad * 16);
    v1.u4 = *(const uint4*)(VB + kh * 72 + quad * 16 + 8);
#pragma unroll
    for (int dd = 0; dd < 8; ++dd) {
      o[dd]     += a * bf2f(v0.s[dd]);
      o[dd + 8] += a * bf2f(v1.s[dd]);
    }
  }
  const size_t rr = (size_t)b * TT + (size_t)lm * 512 + (t >> 4);
  unsigned short* yp = Y + rr * 1024 + (t & 15) * 64 + quad * 16;
  union { uint4 u4; unsigned short s[8]; } o1, o2;
#pragma unroll
  for (int dd = 0; dd < 8; ++dd) o1.s[dd] = f2bf(o[dd]);
#pragma unroll
  for (int dd = 0; dd < 8; ++dd) o2.s[dd] = f2bf(o[8 + dd]);
  ((uint4*)yp)[0] = o1.u4;
  ((uint4*)yp)[1] = o2.u4;
#endif
}

// ---------------------------------------------------------------------------
extern "C" void kernel_launch(void* const* d_in, const int* in_sizes, int n_in,
                              void* d_out, int out_size, void* d_ws, size_t ws_size,
                              hipStream_t stream) {
  const float* x    = (const float*)d_in[0];  // (2,8192,1024) fp32
  const float* Wqkv = (const float*)d_in[1];  // (3072,1024)  fp32
  const float* Wout = (const float*)d_in[2];  // (1024,1024)  fp32
  float* out = (float*)d_out;                 // (2,8192,1024) fp32

  // ws (56 MiB, proven): Y 32 | Wqkvb 6 | Woutb 2 | xb 16
  // d_out (67.1 MB): qkv chunk 50.3 MB at 0, rope table 2 MiB at +52 MiB.
  unsigned short* Y     = (unsigned short*)d_ws;
  unsigned short* Wqkvb = Y + (size_t)BT * 1024;
  unsigned short* Woutb = Wqkvb + (size_t)3072 * 1024;
  unsigned short* xb    = Woutb + (size_t)1024 * 1024;
  unsigned short* qkvC  = (unsigned short*)d_out;
  float2* tab           = (float2*)((char*)d_out + (size_t)52 * 1024 * 1024);

  rope_table_k<<<dim3(TT * 32 / 256), dim3(256), 0, stream>>>(tab);
  cvt_f2b<<<dim3(3072 * 1024 / 4 / 256), dim3(256), 0, stream>>>(Wqkv, Wqkvb, 3072 * 1024 / 4);
  cvt_f2b<<<dim3(1024 * 1024 / 4 / 256), dim3(256), 0, stream>>>(Wout, Woutb, 1024 * 1024 / 4);

  for (int base = 0; base < BT; base += MCH) {
    cvt_f2b<<<dim3(MCH * 1024 / 4 / 256), dim3(256), 0, stream>>>(
        x + (size_t)base * 1024, xb, MCH * 1024 / 4);
    gemm_p3<false><<<dim3((MCH / 256) * (3072 / 128)), dim3(256), 0, stream>>>(
        xb, Wqkvb, qkvC, MCH, 3072, 1024);
    attn_rope_k<<<dim3(MCH / 2), dim3(128), 0, stream>>>(qkvC, tab, Y, base);
  }

  // out = Y @ Wout^T : M=16384, N=1024, K=1024 (fp32 output)
  gemm_p3<true><<<dim3((BT / 256) * (1024 / 128)), dim3(256), 0, stream>>>(
      Y, Woutb, out, BT, 1024, 1024);
}